// Round 8
// baseline (61.801 us; speedup 1.0000x reference)
//
#include <hip/hip_runtime.h>

typedef __attribute__((ext_vector_type(8))) short short8;
typedef __attribute__((ext_vector_type(4))) float f32x4;

// Native __bf16 cast -> hardware cvt (RNE).
__device__ __forceinline__ short f2bf(float f) {
    __bf16 h = (__bf16)f;
    return (short)__builtin_bit_cast(unsigned short, h);
}

__device__ __forceinline__ float fast_tanh(float x) {
    float e2 = __expf(2.f * x);
    return 1.f - 2.f * __builtin_amdgcn_rcpf(e2 + 1.f);
}

__device__ __forceinline__ float fast_sigmoid(float x) {
    return __builtin_amdgcn_rcpf(1.f + __expf(-x));
}

// Kernel 1 (R8): DENSE per-instruction global loads + LDS-bounce re-layout.
// Theory: old loads gave each lane 16B at stride 256B -> 64 scattered 16B
// requests/instr (half-utilized 64B lines); cold (L3 flushed by harness
// restore fills) the HBM path runs at 4.7 TB/s. Dense 1KB/instr loads fix
// per-instruction coalescing; a per-wave LDS slab with XOR swizzle
// (word ^= ((byte>>8)&7)<<2, applied on write AND read; read <=2-way banks)
// restores the (lo,g) fragment layout. BODY/math unchanged.
__global__ __launch_bounds__(256, 2) void attn_kernel(
        const float* __restrict__ enc, const float* __restrict__ s_in,
        const float* __restrict__ W_attn, const float* __restrict__ b_attn,
        const float* __restrict__ v_attn,
        float* __restrict__ ctx_part, float* __restrict__ l_part,
        int NS, int chunk) {
    const int tid  = threadIdx.x;
    const int lane = tid & 63;
    const int wv   = tid >> 6;                 // wave in block
    const int cid  = blockIdx.x % NS;          // S-chunk (shared by all 4 waves)
    const int btile = (blockIdx.x / NS) * 4 + wv;
    const int b0 = btile * 16;
    const int lo = lane & 15;   // batch (B-frag col / D col)
    const int g  = lane >> 4;   // k-group; D rows d = 4g+j (+16t)

    __shared__ __align__(16) float lds_all[4][2][1024];   // 4 waves x 2 slabs x 4KB
    float* const sl0 = &lds_all[wv][0][0];
    float* const sl1 = &lds_all[wv][1][0];

    short8 bW2[2][2];           // A-frag: W_attn[16t+lo][32+32cc+8g+e]
    f32x4 spre[2];
    float v0[4], v1[4];
    {
        const float* sp = s_in + (size_t)(b0 + lo) * 32 + 8 * g;
        float4 sa = *(const float4*)sp;
        float4 sb = *(const float4*)(sp + 4);
        short8 aS;                      // B-frag: s[b0+lo][8g+e]
        aS[0]=f2bf(sa.x); aS[1]=f2bf(sa.y); aS[2]=f2bf(sa.z); aS[3]=f2bf(sa.w);
        aS[4]=f2bf(sb.x); aS[5]=f2bf(sb.y); aS[6]=f2bf(sb.z); aS[7]=f2bf(sb.w);
#pragma unroll
        for (int t = 0; t < 2; ++t) {
            const float* wp = W_attn + (size_t)(16*t + lo) * 96 + 8 * g;
            float4 wa = *(const float4*)wp;
            float4 wb = *(const float4*)(wp + 4);
            short8 bW1;                 // A-frag: W_attn[16t+lo][8g+e]
            bW1[0]=f2bf(wa.x); bW1[1]=f2bf(wa.y); bW1[2]=f2bf(wa.z); bW1[3]=f2bf(wa.w);
            bW1[4]=f2bf(wb.x); bW1[5]=f2bf(wb.y); bW1[6]=f2bf(wb.z); bW1[7]=f2bf(wb.w);
            f32x4 ci;                   // seed at row d = 16t + 4g + j
#pragma unroll
            for (int j = 0; j < 4; ++j) ci[j] = b_attn[16*t + 4*g + j];
            spre[t] = __builtin_amdgcn_mfma_f32_16x16x32_bf16(bW1, aS, ci, 0, 0, 0);
#pragma unroll
            for (int cc = 0; cc < 2; ++cc) {
                const float* qp = W_attn + (size_t)(16*t + lo) * 96 + 32 + 32*cc + 8*g;
                float4 qa = *(const float4*)qp;
                float4 qb = *(const float4*)(qp + 4);
                short8 bb;
                bb[0]=f2bf(qa.x); bb[1]=f2bf(qa.y); bb[2]=f2bf(qa.z); bb[3]=f2bf(qa.w);
                bb[4]=f2bf(qb.x); bb[5]=f2bf(qb.y); bb[6]=f2bf(qb.z); bb[7]=f2bf(qb.w);
                bW2[t][cc] = bb;
            }
        }
#pragma unroll
        for (int j = 0; j < 4; ++j) { v0[j] = v_attn[4*g + j]; v1[j] = v_attn[16 + 4*g + j]; }
    }

    float ctx[16];
#pragma unroll
    for (int i = 0; i < 16; ++i) ctx[i] = 0.f;
    float l_acc = 0.f;

    const size_t rowstride = (size_t)2048 * 64;
    const float* pc = enc + (size_t)(cid * chunk) * rowstride + (size_t)b0 * 64;

    // Loop-invariant swizzled LDS offsets (words).
    const int lhi = lane >> 4;
    const int w_off0 = (0*256 + lane*4) ^ ((((0*4)+lhi)&7)<<2);
    const int w_off1 = (1*256 + lane*4) ^ ((((1*4)+lhi)&7)<<2);
    const int w_off2 = (2*256 + lane*4) ^ ((((2*4)+lhi)&7)<<2);
    const int w_off3 = (3*256 + lane*4) ^ ((((3*4)+lhi)&7)<<2);
    const int rsw = (lo & 7) << 2;
    const int r_offA = (lo*64 + g*8     ) ^ rsw;
    const int r_offB = (lo*64 + g*8 +  4) ^ rsw;
    const int r_offC = (lo*64 + g*8 + 32) ^ rsw;
    const int r_offD = (lo*64 + g*8 + 36) ^ rsw;

    float4 b0_0,b0_1,b0_2,b0_3, b1_0,b1_1,b1_2,b1_3,
           b2_0,b2_1,b2_2,b2_3, b3_0,b3_1,b3_2,b3_3;
    float4 tA, tB, tC, tD;

#define GLOAD(B, ROW) { const float* q = pc + (size_t)(ROW) * rowstride; \
    B##_0 = *(const float4*)(q +        lane*4); \
    B##_1 = *(const float4*)(q +  256 + lane*4); \
    B##_2 = *(const float4*)(q +  512 + lane*4); \
    B##_3 = *(const float4*)(q +  768 + lane*4); }

#define SWRITE(SL, B) { \
    *(float4*)((SL) + w_off0) = B##_0; \
    *(float4*)((SL) + w_off1) = B##_1; \
    *(float4*)((SL) + w_off2) = B##_2; \
    *(float4*)((SL) + w_off3) = B##_3; }

#define SREAD(SL) { \
    tA = *(const float4*)((SL) + r_offA); \
    tB = *(const float4*)((SL) + r_offB); \
    tC = *(const float4*)((SL) + r_offC); \
    tD = *(const float4*)((SL) + r_offD); }

#define BODY() { \
    short8 a0, a1; \
    a0[0]=f2bf(tA.x); a0[1]=f2bf(tA.y); a0[2]=f2bf(tA.z); a0[3]=f2bf(tA.w); \
    a0[4]=f2bf(tB.x); a0[5]=f2bf(tB.y); a0[6]=f2bf(tB.z); a0[7]=f2bf(tB.w); \
    a1[0]=f2bf(tC.x); a1[1]=f2bf(tC.y); a1[2]=f2bf(tC.z); a1[3]=f2bf(tC.w); \
    a1[4]=f2bf(tD.x); a1[5]=f2bf(tD.y); a1[6]=f2bf(tD.z); a1[7]=f2bf(tD.w); \
    f32x4 acc0 = __builtin_amdgcn_mfma_f32_16x16x32_bf16(bW2[0][0], a0, spre[0], 0,0,0); \
    acc0 = __builtin_amdgcn_mfma_f32_16x16x32_bf16(bW2[0][1], a1, acc0, 0,0,0); \
    f32x4 acc1 = __builtin_amdgcn_mfma_f32_16x16x32_bf16(bW2[1][0], a0, spre[1], 0,0,0); \
    acc1 = __builtin_amdgcn_mfma_f32_16x16x32_bf16(bW2[1][1], a1, acc1, 0,0,0); \
    float part = fast_tanh(acc0[0])*v0[0] + fast_tanh(acc0[1])*v0[1] \
               + fast_tanh(acc0[2])*v0[2] + fast_tanh(acc0[3])*v0[3] \
               + fast_tanh(acc1[0])*v1[0] + fast_tanh(acc1[1])*v1[1] \
               + fast_tanh(acc1[2])*v1[2] + fast_tanh(acc1[3])*v1[3]; \
    part += __shfl_xor(part, 16); \
    part += __shfl_xor(part, 32); \
    float w_ = __expf(part); \
    l_acc += w_; \
    ctx[0] += w_*tA.x;  ctx[1] += w_*tA.y;  ctx[2] += w_*tA.z;  ctx[3] += w_*tA.w; \
    ctx[4] += w_*tB.x;  ctx[5] += w_*tB.y;  ctx[6] += w_*tB.z;  ctx[7] += w_*tB.w; \
    ctx[8] += w_*tC.x;  ctx[9] += w_*tC.y;  ctx[10] += w_*tC.z; ctx[11] += w_*tC.w; \
    ctx[12] += w_*tD.x; ctx[13] += w_*tD.y; ctx[14] += w_*tD.z; ctx[15] += w_*tD.w; \
}

    // Pipeline: slab[row&1] holds row's data; bufs b{r&3} hold dense global rows.
    GLOAD(b0, 0); GLOAD(b1, 1); GLOAD(b2, 2);
    SWRITE(sl0, b0);
    int i = 0;
    for (; i + 7 < chunk; i += 4) {
        SREAD(sl0); SWRITE(sl1, b1); GLOAD(b3, i+3); BODY();
        SREAD(sl1); SWRITE(sl0, b2); GLOAD(b0, i+4); BODY();
        SREAD(sl0); SWRITE(sl1, b3); GLOAD(b1, i+5); BODY();
        SREAD(sl1); SWRITE(sl0, b0); GLOAD(b2, i+6); BODY();
    }
    // Epilogue rows i..i+3 == chunk-4..chunk-1 (chunk % 4 == 0, chunk >= 4).
    SREAD(sl0); SWRITE(sl1, b1); GLOAD(b3, i+3); BODY();
    SREAD(sl1); SWRITE(sl0, b2); BODY();
    SREAD(sl0); SWRITE(sl1, b3); BODY();
    SREAD(sl1); BODY();
#undef BODY
#undef SREAD
#undef SWRITE
#undef GLOAD

    float* cp = ctx_part + (size_t)(cid * 2048 + b0 + lo) * 64 + 8 * g;
    *(float4*)(cp)      = make_float4(ctx[0],  ctx[1],  ctx[2],  ctx[3]);
    *(float4*)(cp + 4)  = make_float4(ctx[4],  ctx[5],  ctx[6],  ctx[7]);
    *(float4*)(cp + 32) = make_float4(ctx[8],  ctx[9],  ctx[10], ctx[11]);
    *(float4*)(cp + 36) = make_float4(ctx[12], ctx[13], ctx[14], ctx[15]);
    if (lane < 16) l_part[cid * 2048 + b0 + lane] = l_acc;
}

// Kernel 2: reduce partials -> ctx, then emb + GRU + fc. 8 batches/block,
// thread = (batch_local, h<32).
__global__ __launch_bounds__(256) void finish_kernel(
        const float* __restrict__ dec_in, const float* __restrict__ s_in,
        const float* __restrict__ W_emb, const float* __restrict__ b_emb,
        const float* __restrict__ W_ih, const float* __restrict__ W_hh,
        const float* __restrict__ b_ih, const float* __restrict__ b_hh,
        const float* __restrict__ W_fc, const float* __restrict__ b_fc,
        const float* __restrict__ ctx_part, const float* __restrict__ l_part,
        float* __restrict__ out, int NS) {
    __shared__ __align__(16) float x_lds[8][80];   // [emb(16); ctx(64)]
    __shared__ __align__(16) float s_lds[8][32];
    const int tid = threadIdx.x;
    const int bl = tid >> 5;
    const int h  = tid & 31;
    const int b  = blockIdx.x * 8 + bl;

    float c0 = 0.f, c1 = 0.f, ls = 0.f;
    for (int c = 0; c < NS; ++c) {
        const float* cp = ctx_part + (size_t)(c * 2048 + b) * 64;
        c0 += cp[h];
        c1 += cp[h + 32];
        ls += l_part[c * 2048 + b];
    }
    float inv = 1.f / ls;
    x_lds[bl][16 + h] = c0 * inv;
    x_lds[bl][48 + h] = c1 * inv;
    if (h < 16) x_lds[bl][h] = fmaxf(0.f, dec_in[b] * W_emb[h] + b_emb[h]);
    s_lds[bl][h] = s_in[b * 32 + h];
    __syncthreads();

    float a_r  = b_ih[h]      + b_hh[h];
    float a_z  = b_ih[32 + h] + b_hh[32 + h];
    float gi_n = b_ih[64 + h];
    float gh_n = b_hh[64 + h];
    const float4* xv4 = (const float4*)&x_lds[bl][0];
    const float4* wr4 = (const float4*)(W_ih + 80 * h);
    const float4* wz4 = (const float4*)(W_ih + 80 * (32 + h));
    const float4* wn4 = (const float4*)(W_ih + 80 * (64 + h));
#pragma unroll
    for (int j = 0; j < 20; ++j) {
        float4 x = xv4[j], wr = wr4[j], wz = wz4[j], wn = wn4[j];
        a_r  += x.x*wr.x + x.y*wr.y + x.z*wr.z + x.w*wr.w;
        a_z  += x.x*wz.x + x.y*wz.y + x.z*wz.z + x.w*wz.w;
        gi_n += x.x*wn.x + x.y*wn.y + x.z*wn.z + x.w*wn.w;
    }
    const float4* sv4 = (const float4*)&s_lds[bl][0];
    const float4* hr4 = (const float4*)(W_hh + 32 * h);
    const float4* hz4 = (const float4*)(W_hh + 32 * (32 + h));
    const float4* hn4 = (const float4*)(W_hh + 32 * (64 + h));
#pragma unroll
    for (int j = 0; j < 8; ++j) {
        float4 x = sv4[j], wr = hr4[j], wz = hz4[j], wn = hn4[j];
        a_r  += x.x*wr.x + x.y*wr.y + x.z*wr.z + x.w*wr.w;
        a_z  += x.x*wz.x + x.y*wz.y + x.z*wz.z + x.w*wz.w;
        gh_n += x.x*wn.x + x.y*wn.y + x.z*wn.z + x.w*wn.w;
    }
    float r = fast_sigmoid(a_r);
    float z = fast_sigmoid(a_z);
    float n = fast_tanh(gi_n + r * gh_n);
    float sv = s_lds[bl][h];
    float hn = (1.f - z) * n + z * sv;
    out[2048 + b * 32 + h] = hn;

    float p = hn * W_fc[h] + x_lds[bl][16 + h] * W_fc[32 + h] + x_lds[bl][48 + h] * W_fc[64 + h];
    if (h < 16) p += x_lds[bl][h] * W_fc[96 + h];
    p += __shfl_xor(p, 1); p += __shfl_xor(p, 2); p += __shfl_xor(p, 4);
    p += __shfl_xor(p, 8); p += __shfl_xor(p, 16);
    if (h == 0) out[b] = p + b_fc[0];
}

extern "C" void kernel_launch(void* const* d_in, const int* in_sizes, int n_in,
                              void* d_out, int out_size, void* d_ws, size_t ws_size,
                              hipStream_t stream) {
    const float* dec_in = (const float*)d_in[0];
    const float* s_in   = (const float*)d_in[1];
    const float* enc    = (const float*)d_in[2];
    const float* W_attn = (const float*)d_in[3];
    const float* b_attn = (const float*)d_in[4];
    const float* v_attn = (const float*)d_in[5];
    const float* W_emb  = (const float*)d_in[6];
    const float* b_emb  = (const float*)d_in[7];
    const float* W_ih   = (const float*)d_in[8];
    const float* W_hh   = (const float*)d_in[9];
    const float* b_ih   = (const float*)d_in[10];
    const float* b_hh   = (const float*)d_in[11];
    const float* W_fc   = (const float*)d_in[12];
    const float* b_fc   = (const float*)d_in[13];
    float* out = (float*)d_out;

    int NS = 16;
    while (NS > 1 && (size_t)NS * (2048u * 64u + 2048u) * sizeof(float) > ws_size) NS >>= 1;
    int chunk = 512 / NS;
    float* ctx_part = (float*)d_ws;                       // [NS][2048][64]
    float* l_part   = ctx_part + (size_t)NS * 2048 * 64;  // [NS][2048]

    attn_kernel<<<dim3(32 * NS), dim3(256), 0, stream>>>(
        enc, s_in, W_attn, b_attn, v_attn, ctx_part, l_part, NS, chunk);
    finish_kernel<<<dim3(256), dim3(256), 0, stream>>>(
        dec_in, s_in, W_emb, b_emb, W_ih, W_hh, b_ih, b_hh, W_fc, b_fc,
        ctx_part, l_part, out, NS);
}